// Round 5
// baseline (2515.149 us; speedup 1.0000x reference)
//
#include <hip/hip_runtime.h>
#include <cstdint>
#include <cstddef>

#define B_TOTAL 65536
#define SDIM 64
#define ADIM 32
#define LDIM 64
#define HDIM 1024
#define NEMB 1024
#define TAU 0.125f

typedef __attribute__((ext_vector_type(8))) short short8;
typedef __attribute__((ext_vector_type(4))) float f32x4;

__device__ inline unsigned short f2bf(float f) {
    unsigned int u = __float_as_uint(f);
    u += 0x7fffu + ((u >> 16) & 1u);
    return (unsigned short)(u >> 16);
}
__device__ inline float bf2f(unsigned short s) {
    return __uint_as_float(((unsigned int)s) << 16);
}

// async global->LDS, 16B per lane; LDS dest = wave-uniform base + lane*16.
__device__ inline void gload16(const unsigned short* g, unsigned short* l) {
    __builtin_amdgcn_global_load_lds(
        (__attribute__((address_space(1))) void*)(g),
        (__attribute__((address_space(3))) void*)(l), 16, 0, 0);
}

// ---------------------------------------------------------------------------
__global__ void cb_norms(const float* __restrict__ codebook, float* __restrict__ cbn)
{
    int i = blockIdx.x * 256 + threadIdx.x;
    if (i < NEMB) {
        float s = 0.f;
#pragma unroll
        for (int k = 0; k < LDIM; ++k) {
            float v = codebook[(size_t)i * LDIM + k];
            s = fmaf(v, v, s);
        }
        cbn[i] = s;
    }
}

__global__ void zero_ctr(int* ctr) { if (threadIdx.x == 0) *ctr = 0; }

// ---------------------------------------------------------------------------
// Weight pre-transform: W[K][N] fp32 -> bf16 plane(s), MFMA-B-ready layout.
// ---------------------------------------------------------------------------
template <int NT, int BN>
__global__ __launch_bounds__(256) void w_xform(
    const float* __restrict__ W, int K, int N,
    unsigned short* __restrict__ Ph, unsigned short* __restrict__ Pl)
{
    __shared__ float Ws[32][BN + 4];
    const int tid = threadIdx.x;
    const int ks = blockIdx.x, nb = blockIdx.y;
    const int k0 = ks * 32, n0 = nb * BN;
    constexpr int LT = 32 * (BN / 4);
#pragma unroll
    for (int it = 0; it < (LT + 255) / 256; ++it) {
        int idx = tid + it * 256;
        if (LT % 256 == 0 || idx < LT) {
            int k = idx / (BN / 4);
            int nf = idx % (BN / 4);
            *(f32x4*)&Ws[k][nf * 4] =
                *(const f32x4*)&W[(size_t)(k0 + k) * N + n0 + nf * 4];
        }
    }
    __syncthreads();
    const int KS = K >> 5;
    size_t bo = ((size_t)nb * KS + ks) * (BN * 32);
    constexpr int WT = BN * 4;
#pragma unroll
    for (int it = 0; it < (WT + 255) / 256; ++it) {
        int idx = tid + it * 256;
        if (WT % 256 == 0 || idx < WT) {
            int kb = idx / BN;
            int n = idx % BN;
            short8 h, l;
#pragma unroll
            for (int j = 0; j < 8; ++j) {
                float x = Ws[kb * 8 + j][n];
                unsigned short hb_ = f2bf(x);
                h[j] = (short)hb_;
                if (NT == 3) l[j] = (short)f2bf(x - bf2f(hb_));
            }
            *(short8*)&Ph[bo + (size_t)idx * 8] = h;
            if (NT == 3) *(short8*)&Pl[bo + (size_t)idx * 8] = l;
        }
    }
}

// ---------------------------------------------------------------------------
// BF16 MFMA GEMM, double-buffered prefetch (m97 pattern) + XCD swizzle.
// A plane row-major [row][K] bf16 (hi, + lo if NT==3); W pre-transformed.
// Loop: sync (drain loads issued last iter) -> issue stage(next) -> compute.
// BN==128 grids are 1D mt*8 with bijective XCD remap (nb-fastest per XCD:
// 8 consecutive blocks on one XCD share the A-tile; W slices stay L2-hot).
// ---------------------------------------------------------------------------
template <int NT, int BN, int OUT, int ACT>
__global__ __launch_bounds__(256, 2) void mfma_gemm(
    const unsigned short* __restrict__ Ah_g, const unsigned short* __restrict__ Al_g,
    int K,
    const unsigned short* __restrict__ Wh, const unsigned short* __restrict__ Wl,
    const float* __restrict__ bias,
    void* __restrict__ out0, void* __restrict__ out1, int NTOT)
{
    constexpr int NWC = (BN == 128) ? 2 : 1;
    constexpr int WM = (BN == 128) ? 4 : 2;
    constexpr int WN = (BN == 32) ? 2 : 4;
    constexpr int ABUF = (NT == 3) ? 8192 : 4096;           // shorts per buffer (A)
    constexpr int BBUF = 4 * BN * 8 * ((NT == 3) ? 2 : 1);  // shorts per buffer (B)
    constexpr int BUFSH = ABUF + BBUF;

    __shared__ unsigned short smem[2 * BUFSH];

    const int tid = threadIdx.x;
    int row_t, nb;
    if constexpr (BN == 128) {
        int per = gridDim.x >> 3;        // == mt (mt % 8 == 0 guaranteed by host)
        int xcd = blockIdx.x & 7;
        int lid = blockIdx.x >> 3;
        int tile = xcd * per + lid;
        row_t = tile >> 3;
        nb = tile & 7;
    } else {
        row_t = blockIdx.x;
        nb = 0;
    }
    const int m0 = row_t * 128;
    const int n0 = nb * BN;
    const int w = tid >> 6, lane = tid & 63;
    const int g = lane >> 4, lr = lane & 15;
    const int wrow0 = (w / NWC) * (WM * 16);
    const int wcol0 = (w % NWC) * (WN * 16);
    const int KS = K >> 5;

    auto stage = [&](unsigned short* buf, int ks) {
        unsigned short* Ah = buf;
        unsigned short* Al = buf + 4096;
        unsigned short* Bh = buf + ABUF;
        unsigned short* Bl = Bh + 4 * BN * 8;
        // A tile: 512 tasks t=(kb*128+row), LDS slot t (16B each)
#pragma unroll
        for (int it = 0; it < 2; ++it) {
            int t0 = it * 256 + w * 64;
            int t = t0 + lane;
            int row = t & 127, kb = t >> 7;
            size_t go = (size_t)(m0 + row) * K + ks * 32 + kb * 8;
            gload16(Ah_g + go, Ah + (size_t)t0 * 8);
            if constexpr (NT == 3) gload16(Al_g + go, Al + (size_t)t0 * 8);
        }
        // B tile: linear copy of pre-transformed block
        size_t bo = ((size_t)nb * KS + ks) * (BN * 32);
        constexpr int BT = 4 * BN;
        if constexpr (BT >= 256) {
#pragma unroll
            for (int it = 0; it < BT / 256; ++it) {
                int t0 = it * 256 + w * 64;
                size_t go = bo + (size_t)(t0 + lane) * 8;
                gload16(Wh + go, Bh + (size_t)t0 * 8);
                if constexpr (NT == 3) gload16(Wl + go, Bl + (size_t)t0 * 8);
            }
        } else {
            if (tid < BT) {
                int t0 = w * 64;
                size_t go = bo + (size_t)(t0 + lane) * 8;
                gload16(Wh + go, Bh + (size_t)t0 * 8);
                if constexpr (NT == 3) gload16(Wl + go, Bl + (size_t)t0 * 8);
            }
        }
    };

    f32x4 acc[WM][WN];
#pragma unroll
    for (int m = 0; m < WM; ++m)
#pragma unroll
        for (int n = 0; n < WN; ++n) {
            acc[m][n][0] = 0.f; acc[m][n][1] = 0.f;
            acc[m][n][2] = 0.f; acc[m][n][3] = 0.f;
        }

    stage(smem, 0);   // prologue into buffer 0

    for (int ks = 0; ks < KS; ++ks) {
        __syncthreads();   // drains vmcnt: buf[cur] staged (issued a full phase ago)
        unsigned short* buf = smem + (size_t)(ks & 1) * BUFSH;
        if (ks + 1 < KS)
            stage(smem + (size_t)((ks + 1) & 1) * BUFSH, ks + 1);   // flies during MFMA

        unsigned short* Ah = buf;
        unsigned short* Al = buf + 4096;
        unsigned short* Bh = buf + ABUF;
        unsigned short* Bl = Bh + 4 * BN * 8;

        short8 ah[WM], bh[WN];
        short8 al[WM], bl[WN];
#pragma unroll
        for (int m = 0; m < WM; ++m) {
            int ro = (g << 7) + wrow0 + m * 16 + lr;
            ah[m] = *(const short8*)&Ah[ro * 8];
            if constexpr (NT == 3) al[m] = *(const short8*)&Al[ro * 8];
        }
#pragma unroll
        for (int n = 0; n < WN; ++n) {
            int co = g * BN + wcol0 + n * 16 + lr;
            bh[n] = *(const short8*)&Bh[co * 8];
            if constexpr (NT == 3) bl[n] = *(const short8*)&Bl[co * 8];
        }
#pragma unroll
        for (int m = 0; m < WM; ++m)
#pragma unroll
            for (int n = 0; n < WN; ++n) {
                acc[m][n] = __builtin_amdgcn_mfma_f32_16x16x32_bf16(
                    ah[m], bh[n], acc[m][n], 0, 0, 0);
                if constexpr (NT == 3) {
                    acc[m][n] = __builtin_amdgcn_mfma_f32_16x16x32_bf16(
                        ah[m], bl[n], acc[m][n], 0, 0, 0);
                    acc[m][n] = __builtin_amdgcn_mfma_f32_16x16x32_bf16(
                        al[m], bh[n], acc[m][n], 0, 0, 0);
                }
            }
    }

    // ---- epilogue: bias + act, LDS transpose, coalesced stores ----
    float bv[WN];
#pragma unroll
    for (int n = 0; n < WN; ++n) bv[n] = bias[n0 + wcol0 + n * 16 + lr];

    unsigned short* Sb = smem;
    float* Sf = (float*)smem;
    constexpr int NPASS = (OUT == 0) ? 2 : 1;

#pragma unroll
    for (int p = 0; p < NPASS; ++p) {
        __syncthreads();
#pragma unroll
        for (int m = 0; m < WM; ++m)
#pragma unroll
            for (int n = 0; n < WN; ++n)
#pragma unroll
                for (int q = 0; q < 4; ++q) {
                    int rl = wrow0 + m * 16 + g * 4 + q;
                    int cl = wcol0 + n * 16 + lr;
                    float x = acc[m][n][q] + bv[n];
                    if (ACT == 0) x = fmaxf(x, 0.f);
                    else x = tanhf(x);
                    if constexpr (OUT == 2) {
                        Sf[rl * BN + cl] = x;
                    } else {
                        unsigned short hb_ = f2bf(x);
                        Sb[rl * BN + cl] = (p == 0) ? hb_ : f2bf(x - bf2f(hb_));
                    }
                }
        __syncthreads();
        if constexpr (OUT == 2) {
            constexpr int SL = BN / 4;
#pragma unroll
            for (int it = 0; it < (128 * SL) / 256; ++it) {
                int idx = tid + it * 256;
                int row = idx / SL, sl = idx % SL;
                *(f32x4*)((float*)out0 + (size_t)(m0 + row) * NTOT + n0 + sl * 4)
                    = *(const f32x4*)&Sf[row * BN + sl * 4];
            }
        } else {
            constexpr int SL = BN / 8;
            unsigned short* dst = (unsigned short*)((p == 0) ? out0 : out1);
#pragma unroll
            for (int it = 0; it < (128 * SL) / 256; ++it) {
                int idx = tid + it * 256;
                int row = idx / SL, sl = idx % SL;
                *(short8*)&dst[(size_t)(m0 + row) * NTOT + n0 + sl * 8]
                    = *(const short8*)&Sb[row * BN + sl * 8];
            }
        }
    }
}

// ---------------------------------------------------------------------------
__global__ void sa_pre(const float* __restrict__ state, const float* __restrict__ action,
                       unsigned short* __restrict__ saH, unsigned short* __restrict__ saL)
{
    int idx = blockIdx.x * 256 + threadIdx.x;
    int row = idx / 12, q = idx % 12;
    const float* src = (q < 8) ? (state + (size_t)row * 64 + q * 8)
                               : (action + (size_t)row * 32 + (q - 8) * 8);
    f32x4 v0 = *(const f32x4*)src;
    f32x4 v1 = *(const f32x4*)(src + 4);
    short8 h, l;
#pragma unroll
    for (int j = 0; j < 8; ++j) {
        float x = (j < 4) ? v0[j] : v1[j - 4];
        unsigned short hb_ = f2bf(x);
        h[j] = (short)hb_;
        l[j] = (short)f2bf(x - bf2f(hb_));
    }
    *(short8*)&saH[(size_t)row * 96 + q * 8] = h;
    *(short8*)&saL[(size_t)row * 96 + q * 8] = l;
}

__global__ void xz_pre(const float* __restrict__ state, unsigned short* __restrict__ xz)
{
    int idx = blockIdx.x * 256 + threadIdx.x;
    int row = idx >> 4, q = idx & 15;
    f32x4 v = *(const f32x4*)&state[(size_t)row * 64 + q * 4];
    unsigned short o[4];
    o[0] = f2bf(v[0]); o[1] = f2bf(v[1]); o[2] = f2bf(v[2]); o[3] = f2bf(v[3]);
    *(uint2*)&xz[(size_t)row * 128 + q * 4] = *(uint2*)o;
}

// ---------------------------------------------------------------------------
// Fused VQ + latent head (unchanged semantics).
// ---------------------------------------------------------------------------
__global__ __launch_bounds__(256) void vq_latent(
    const float* __restrict__ midz,
    const float* __restrict__ codebook,
    const float* __restrict__ cbn,
    const float* __restrict__ mean_w, const float* __restrict__ mean_b,
    const float* __restrict__ logstd_w, const float* __restrict__ logstd_b,
    const float* __restrict__ eps,
    float* __restrict__ mean_out,
    float* __restrict__ std_out,
    unsigned short* __restrict__ xz,
    int* __restrict__ ctr, int* __restrict__ list)
{
    __shared__ float smem[13120];
    float* Zt = smem;                    // [64][132]
    float* Ct = smem + 8448;             // [64][68]
    float* cn = smem + 12800;            // [64]
    float* zn = smem + 12864;            // [128]
    int* sidx = (int*)(smem + 12992);    // [128]

    const int tid = threadIdx.x;
    const int m0 = blockIdx.x * 128;
    const int r = tid >> 4;
    const int c = tid & 15;

#pragma unroll
    for (int it = 0; it < 8; ++it) {
        int idx = tid + it * 256;
        int row = idx >> 4;
        int f = idx & 15;
        float4 v = *(const float4*)(midz + (size_t)(m0 + row) * 64 + f * 4);
        Zt[(f * 4 + 0) * 132 + row] = v.x;
        Zt[(f * 4 + 1) * 132 + row] = v.y;
        Zt[(f * 4 + 2) * 132 + row] = v.z;
        Zt[(f * 4 + 3) * 132 + row] = v.w;
    }
    __syncthreads();
    if (tid < 128) {
        float s = 0.f;
#pragma unroll
        for (int k = 0; k < 64; ++k) {
            float v = Zt[k * 132 + tid];
            s = fmaf(v, v, s);
        }
        zn[tid] = s;
    }

    float best[8], sec[8];
    int bidx[8];
#pragma unroll
    for (int i = 0; i < 8; ++i) { best[i] = 3.4e38f; sec[i] = 3.4e38f; bidx[i] = 0x7fffffff; }

    for (int ch = 0; ch < 16; ++ch) {
        int e0 = ch * 64;
        __syncthreads();
#pragma unroll
        for (int it = 0; it < 4; ++it) {
            int idx = tid + it * 256;
            int e = idx >> 4;
            int f = idx & 15;
            float4 v = *(const float4*)(codebook + (size_t)(e0 + e) * 64 + f * 4);
            Ct[(f * 4 + 0) * 68 + e] = v.x;
            Ct[(f * 4 + 1) * 68 + e] = v.y;
            Ct[(f * 4 + 2) * 68 + e] = v.z;
            Ct[(f * 4 + 3) * 68 + e] = v.w;
        }
        if (tid < 64) cn[tid] = cbn[e0 + tid];
        __syncthreads();

        float acc[8][4];
#pragma unroll
        for (int i = 0; i < 8; ++i)
#pragma unroll
            for (int j = 0; j < 4; ++j) acc[i][j] = 0.f;

#pragma unroll 8
        for (int kk = 0; kk < 64; ++kk) {
            float a[8], b[4];
            float4 av0 = *(const float4*)&Zt[kk * 132 + r * 8];
            float4 av1 = *(const float4*)&Zt[kk * 132 + r * 8 + 4];
            a[0] = av0.x; a[1] = av0.y; a[2] = av0.z; a[3] = av0.w;
            a[4] = av1.x; a[5] = av1.y; a[6] = av1.z; a[7] = av1.w;
            float4 bv = *(const float4*)&Ct[kk * 68 + c * 4];
            b[0] = bv.x; b[1] = bv.y; b[2] = bv.z; b[3] = bv.w;
#pragma unroll
            for (int i = 0; i < 8; ++i)
#pragma unroll
                for (int j = 0; j < 4; ++j)
                    acc[i][j] = fmaf(a[i], b[j], acc[i][j]);
        }
#pragma unroll
        for (int i = 0; i < 8; ++i) {
            float zni = zn[r * 8 + i];
#pragma unroll
            for (int j = 0; j < 4; ++j) {
                int e = c * 4 + j;
                float s = (zni + cn[e]) - 2.0f * acc[i][j];
                int gi = e0 + e;
                if (s < best[i] || (s == best[i] && gi < bidx[i])) {
                    sec[i] = best[i];
                    best[i] = s;
                    bidx[i] = gi;
                } else {
                    sec[i] = fminf(sec[i], s);
                }
            }
        }
    }

#pragma unroll
    for (int i = 0; i < 8; ++i) {
#pragma unroll
        for (int m = 1; m < 16; m <<= 1) {
            float ob = __shfl_xor(best[i], m, 64);
            int oi = __shfl_xor(bidx[i], m, 64);
            float os = __shfl_xor(sec[i], m, 64);
            if (ob < best[i] || (ob == best[i] && oi < bidx[i])) {
                sec[i] = fminf(best[i], os);
                best[i] = ob;
                bidx[i] = oi;
            } else {
                sec[i] = fminf(sec[i], ob);
            }
        }
    }
    __syncthreads();
    if (c == 0) {
#pragma unroll
        for (int i = 0; i < 8; ++i) {
            sidx[r * 8 + i] = bidx[i];
            if (sec[i] - best[i] < TAU) {
                int p = atomicAdd(ctr, 1);
                list[p] = m0 + r * 8 + i;
            }
        }
    }

    float* mw = smem;
    float* lw = smem + 4160;
#pragma unroll
    for (int it = 0; it < 4; ++it) {
        int idx = tid + it * 256;
        int k = idx >> 4;
        int f = idx & 15;
        float4 v = *(const float4*)(mean_w + (size_t)k * 64 + f * 4);
        mw[k * 65 + f * 4 + 0] = v.x;
        mw[k * 65 + f * 4 + 1] = v.y;
        mw[k * 65 + f * 4 + 2] = v.z;
        mw[k * 65 + f * 4 + 3] = v.w;
        float4 w2 = *(const float4*)(logstd_w + (size_t)k * 64 + f * 4);
        lw[k * 65 + f * 4 + 0] = w2.x;
        lw[k * 65 + f * 4 + 1] = w2.y;
        lw[k * 65 + f * 4 + 2] = w2.z;
        lw[k * 65 + f * 4 + 3] = w2.w;
    }
    __syncthreads();

    {
        int row = tid >> 1;
        int d0 = (tid & 1) * 32;
        int e = sidx[row];
        const float* cb = codebook + (size_t)e * 64;
        float mv[32], lv[32];
#pragma unroll
        for (int d = 0; d < 32; ++d) {
            mv[d] = mean_b[d0 + d];
            lv[d] = logstd_b[d0 + d];
        }
        for (int k = 0; k < 64; ++k) {
            float zk = cb[k];
#pragma unroll
            for (int d = 0; d < 32; ++d) {
                mv[d] = fmaf(zk, mw[k * 65 + d0 + d], mv[d]);
                lv[d] = fmaf(zk, lw[k * 65 + d0 + d], lv[d]);
            }
        }
        size_t ro = (size_t)(m0 + row) * 64 + d0;
        size_t xo = (size_t)(m0 + row) * 128 + 64 + d0;
#pragma unroll
        for (int d = 0; d < 32; ++d) {
            float mean = mv[d];
            float ls = fminf(fmaxf(lv[d], -4.f), 15.f);
            float sd = expf(ls);
            float z = fmaf(sd, eps[ro + d], mean);
            mean_out[ro + d] = mean;
            std_out[ro + d] = sd;
            xz[xo + d] = f2bf(z);
        }
    }
}

// ---------------------------------------------------------------------------
// Exact fp32 recompute of flagged rows. Inner k-loops unrolled x8 with
// register-staged weights (32 loads in flight -> latency amortized).
// ---------------------------------------------------------------------------
#define FROWS 8
__global__ __launch_bounds__(256) void fix_rows(
    const int* __restrict__ ctr, const int* __restrict__ list, int r0,
    const float* __restrict__ state, const float* __restrict__ action,
    const float* __restrict__ eps,
    const float* __restrict__ ew1, const float* __restrict__ eb1,
    const float* __restrict__ ew2, const float* __restrict__ eb2,
    const float* __restrict__ ew3, const float* __restrict__ eb3,
    const float* __restrict__ mean_w, const float* __restrict__ mean_b,
    const float* __restrict__ logstd_w, const float* __restrict__ logstd_b,
    const float* __restrict__ codebook, const float* __restrict__ cbn,
    float* __restrict__ mean_out, float* __restrict__ std_out,
    unsigned short* __restrict__ xz)
{
    __shared__ float in_s[FROWS][96];
    __shared__ float buf[FROWS][1024];
    __shared__ float mzs[FROWS][64];
    __shared__ float zns[FROWS];
    __shared__ int rows_s[FROWS];
    __shared__ int am_s[FROWS];

    const int tid = threadIdx.x;
    const int cnt = *ctr;

    for (int base = blockIdx.x * FROWS; base < cnt; base += gridDim.x * FROWS) {
        int nr = min(FROWS, cnt - base);
        __syncthreads();
        if (tid < FROWS) rows_s[tid] = list[base + ((tid < nr) ? tid : 0)];
        __syncthreads();
        for (int t = tid; t < FROWS * 96; t += 256) {
            int rr = t / 96, k = t % 96;
            size_t grow = (size_t)(r0 + rows_s[rr]);
            in_s[rr][k] = (k < 64) ? state[grow * 64 + k]
                                   : action[grow * 32 + (k - 64)];
        }
        __syncthreads();
        // ---- L1 ----
        float a1[FROWS][4];
#pragma unroll
        for (int rr = 0; rr < FROWS; ++rr)
#pragma unroll
            for (int j = 0; j < 4; ++j) a1[rr][j] = 0.f;
        for (int k0 = 0; k0 < 96; k0 += 8) {
            float wv[8][4];
#pragma unroll
            for (int kk = 0; kk < 8; ++kk)
#pragma unroll
                for (int j = 0; j < 4; ++j)
                    wv[kk][j] = ew1[(size_t)(k0 + kk) * 1024 + tid + j * 256];
#pragma unroll
            for (int kk = 0; kk < 8; ++kk)
#pragma unroll
                for (int rr = 0; rr < FROWS; ++rr) {
                    float av = in_s[rr][k0 + kk];
                    a1[rr][0] = fmaf(av, wv[kk][0], a1[rr][0]);
                    a1[rr][1] = fmaf(av, wv[kk][1], a1[rr][1]);
                    a1[rr][2] = fmaf(av, wv[kk][2], a1[rr][2]);
                    a1[rr][3] = fmaf(av, wv[kk][3], a1[rr][3]);
                }
        }
#pragma unroll
        for (int rr = 0; rr < FROWS; ++rr)
#pragma unroll
            for (int j = 0; j < 4; ++j)
                buf[rr][tid + j * 256] = fmaxf(a1[rr][j] + eb1[tid + j * 256], 0.f);
        __syncthreads();
        // ---- L2 ----
        float a2[FROWS][4];
#pragma unroll
        for (int rr = 0; rr < FROWS; ++rr)
#pragma unroll
            for (int j = 0; j < 4; ++j) a2[rr][j] = 0.f;
        for (int k0 = 0; k0 < 1024; k0 += 8) {
            float wv[8][4];
#pragma unroll
            for (int kk = 0; kk < 8; ++kk)
#pragma unroll
                for (int j = 0; j < 4; ++j)
                    wv[kk][j] = ew2[(size_t)(k0 + kk) * 1024 + tid + j * 256];
#pragma unroll
            for (int kk = 0; kk < 8; ++kk)
#pragma unroll
                for (int rr = 0; rr < FROWS; ++rr) {
                    float av = buf[rr][k0 + kk];
                    a2[rr][0] = fmaf(av, wv[kk][0], a2[rr][0]);
                    a2[rr][1] = fmaf(av, wv[kk][1], a2[rr][1]);
                    a2[rr][2] = fmaf(av, wv[kk][2], a2[rr][2]);
                    a2[rr][3] = fmaf(av, wv[kk][3], a2[rr][3]);
                }
        }
        __syncthreads();
#pragma unroll
        for (int rr = 0; rr < FROWS; ++rr)
#pragma unroll
            for (int j = 0; j < 4; ++j)
                buf[rr][tid + j * 256] = fmaxf(a2[rr][j] + eb2[tid + j * 256], 0.f);
        __syncthreads();
        // ---- L3 ----
#pragma unroll
        for (int jo = 0; jo < 2; ++jo) {
            int o = tid + jo * 256;
            int rr = o >> 6, d = o & 63;
            float s = eb3[d];
            for (int k0 = 0; k0 < 1024; k0 += 8) {
                float wv[8];
#pragma unroll
                for (int kk = 0; kk < 8; ++kk)
                    wv[kk] = ew3[(size_t)(k0 + kk) * 64 + d];
#pragma unroll
                for (int kk = 0; kk < 8; ++kk)
                    s = fmaf(buf[rr][k0 + kk], wv[kk], s);
            }
            mzs[rr][d] = fmaxf(s, 0.f);
        }
        __syncthreads();
        if (tid < FROWS) {
            float s = 0.f;
#pragma unroll
            for (int k = 0; k < 64; ++k) s = fmaf(mzs[tid][k], mzs[tid][k], s);
            zns[tid] = s;
        }
        __syncthreads();
        // ---- argmin over 1024 codes (4 per thread) ----
        float bb[FROWS];
        int bi[FROWS];
#pragma unroll
        for (int rr = 0; rr < FROWS; ++rr) { bb[rr] = 3.4e38f; bi[rr] = 0x7fffffff; }
#pragma unroll
        for (int j = 0; j < 4; ++j) {
            int code = tid + j * 256;
            float dot[FROWS];
#pragma unroll
            for (int rr = 0; rr < FROWS; ++rr) dot[rr] = 0.f;
            for (int k0 = 0; k0 < 64; k0 += 8) {
                float cv[8];
#pragma unroll
                for (int kk = 0; kk < 8; ++kk)
                    cv[kk] = codebook[(size_t)code * 64 + k0 + kk];
#pragma unroll
                for (int kk = 0; kk < 8; ++kk)
#pragma unroll
                    for (int rr = 0; rr < FROWS; ++rr)
                        dot[rr] = fmaf(mzs[rr][k0 + kk], cv[kk], dot[rr]);
            }
            float cnv = cbn[code];
#pragma unroll
            for (int rr = 0; rr < FROWS; ++rr) {
                float s = (zns[rr] + cnv) - 2.0f * dot[rr];
                if (s < bb[rr] || (s == bb[rr] && code < bi[rr])) {
                    bb[rr] = s; bi[rr] = code;
                }
            }
        }
        float* sv = &buf[0][0];
        int* si = (int*)(&buf[0][0] + 2048);
#pragma unroll
        for (int rr = 0; rr < FROWS; ++rr) {
            sv[rr * 256 + tid] = bb[rr];
            si[rr * 256 + tid] = bi[rr];
        }
        __syncthreads();
        if (tid < FROWS) {
            float b = 3.4e38f;
            int ix = 0x7fffffff;
            for (int t = 0; t < 256; ++t) {
                float v = sv[tid * 256 + t];
                int iv = si[tid * 256 + t];
                if (v < b || (v == b && iv < ix)) { b = v; ix = iv; }
            }
            am_s[tid] = ix;
        }
        __syncthreads();
        // ---- outputs ----
#pragma unroll
        for (int jo = 0; jo < 2; ++jo) {
            int o = tid + jo * 256;
            int rr = o >> 6, d = o & 63;
            if (rr < nr) {
                int e = am_s[rr];
                size_t grow = (size_t)(r0 + rows_s[rr]);
                float mv = mean_b[d], lv = logstd_b[d];
                const float* cb = codebook + (size_t)e * 64;
                for (int k0 = 0; k0 < 64; k0 += 8) {
                    float c1[8], c2[8], c3[8];
#pragma unroll
                    for (int kk = 0; kk < 8; ++kk) {
                        c1[kk] = cb[k0 + kk];
                        c2[kk] = mean_w[(size_t)(k0 + kk) * 64 + d];
                        c3[kk] = logstd_w[(size_t)(k0 + kk) * 64 + d];
                    }
#pragma unroll
                    for (int kk = 0; kk < 8; ++kk) {
                        mv = fmaf(c1[kk], c2[kk], mv);
                        lv = fmaf(c1[kk], c3[kk], lv);
                    }
                }
                float ls = fminf(fmaxf(lv, -4.f), 15.f);
                float sd = expf(ls);
                float z = fmaf(sd, eps[grow * 64 + d], mv);
                mean_out[grow * 64 + d] = mv;
                std_out[grow * 64 + d] = sd;
                xz[(size_t)rows_s[rr] * 128 + 64 + d] = f2bf(z);
            }
        }
        __syncthreads();
    }
}

// ---------------------------------------------------------------------------
extern "C" void kernel_launch(void* const* d_in, const int* in_sizes, int n_in,
                              void* d_out, int out_size, void* d_ws, size_t ws_size,
                              hipStream_t stream)
{
    const float* state    = (const float*)d_in[0];
    const float* action   = (const float*)d_in[1];
    const float* eps      = (const float*)d_in[2];
    const float* enc_w1   = (const float*)d_in[3];
    const float* enc_b1   = (const float*)d_in[4];
    const float* enc_w2   = (const float*)d_in[5];
    const float* enc_b2   = (const float*)d_in[6];
    const float* enc_w3   = (const float*)d_in[7];
    const float* enc_b3   = (const float*)d_in[8];
    const float* mean_w   = (const float*)d_in[9];
    const float* mean_b   = (const float*)d_in[10];
    const float* logstd_w = (const float*)d_in[11];
    const float* logstd_b = (const float*)d_in[12];
    const float* codebook = (const float*)d_in[13];
    const float* dec_w1   = (const float*)d_in[14];
    const float* dec_b1   = (const float*)d_in[15];
    const float* dec_w2   = (const float*)d_in[16];
    const float* dec_b2   = (const float*)d_in[17];
    const float* dec_w3   = (const float*)d_in[18];
    const float* dec_b3   = (const float*)d_in[19];

    float* out = (float*)d_out;
    float* u_out = out;
    float* mean_out = out + (size_t)B_TOTAL * 32;
    float* std_out = mean_out + (size_t)B_TOTAL * 64;

    // ---- fixed ws region ----
    char* base = (char*)d_ws;
    float* cbn = (float*)base;                                   // 4096
    unsigned short* W1h = (unsigned short*)(base + 4096);        // 196608
    unsigned short* W1l = (unsigned short*)(base + 200704);      // 196608
    unsigned short* W2h = (unsigned short*)(base + 397312);      // 2097152
    unsigned short* W2l = (unsigned short*)(base + 2494464);     // 2097152
    unsigned short* W3h = (unsigned short*)(base + 4591616);     // 131072
    unsigned short* W3l = (unsigned short*)(base + 4722688);     // 131072
    unsigned short* W4h = (unsigned short*)(base + 4853760);     // 262144
    unsigned short* W5h = (unsigned short*)(base + 5115904);     // 2097152
    unsigned short* W6h = (unsigned short*)(base + 7213056);     // 65536
    int* ctr            = (int*)(base + 7278592);                // 256
    int* flag_list      = (int*)(base + 7278848);                // 262144
    const size_t FIXED  = 7540992;

    // per-row: saH 192 + saL 192 + h1H 2048 + h1L 2048 + h2H 2048 + h2L 2048
    //          + mz 256 + xz 256 = 11088 B ; C multiple of 1024 (XCD swizzle)
    const size_t per_row = 11088;
    long maxC = (ws_size > FIXED) ? (long)((ws_size - FIXED) / per_row) : 0;
    int C = (int)(maxC / 1024) * 1024;
    if (C > B_TOTAL) C = B_TOTAL;
    if (C < 1024) C = 1024;

    char* dyn = base + FIXED;
    unsigned short* saH = (unsigned short*)dyn;                   // [C,96]
    unsigned short* saL = saH + (size_t)C * 96;
    unsigned short* h1H = saL + (size_t)C * 96;                   // [C,1024]
    unsigned short* h1L = h1H + (size_t)C * 1024;
    unsigned short* h2H = h1L + (size_t)C * 1024;
    unsigned short* h2L = h2H + (size_t)C * 1024;
    float* mz = (float*)(h2L + (size_t)C * 1024);                 // [C,64]
    unsigned short* xz = (unsigned short*)(mz + (size_t)C * 64);  // [C,128]
    unsigned short* hc = h1H;   // decoder reuse
    unsigned short* hd = h2H;

    // ---- once per call ----
    cb_norms<<<dim3(4), dim3(256), 0, stream>>>(codebook, cbn);
    w_xform<3, 128><<<dim3(3, 8), dim3(256), 0, stream>>>(enc_w1, 96, 1024, W1h, W1l);
    w_xform<3, 128><<<dim3(32, 8), dim3(256), 0, stream>>>(enc_w2, 1024, 1024, W2h, W2l);
    w_xform<3, 64><<<dim3(32, 1), dim3(256), 0, stream>>>(enc_w3, 1024, 64, W3h, W3l);
    w_xform<1, 128><<<dim3(4, 8), dim3(256), 0, stream>>>(dec_w1, 128, 1024, W4h, nullptr);
    w_xform<1, 128><<<dim3(32, 8), dim3(256), 0, stream>>>(dec_w2, 1024, 1024, W5h, nullptr);
    w_xform<1, 32><<<dim3(32, 1), dim3(256), 0, stream>>>(dec_w3, 1024, 32, W6h, nullptr);

    for (int r0 = 0; r0 < B_TOTAL; r0 += C) {
        int M = (r0 + C <= B_TOTAL) ? C : (B_TOTAL - r0);
        int mt = M / 128;          // multiple of 8 (M multiple of 1024)

        sa_pre<<<dim3(M * 12 / 256), dim3(256), 0, stream>>>(
            state + (size_t)r0 * SDIM, action + (size_t)r0 * ADIM, saH, saL);

        // encoder: 3-term split bf16 MFMA
        mfma_gemm<3, 128, 0, 0><<<dim3(mt * 8), dim3(256), 0, stream>>>(
            saH, saL, 96, W1h, W1l, enc_b1, h1H, h1L, 1024);
        mfma_gemm<3, 128, 0, 0><<<dim3(mt * 8), dim3(256), 0, stream>>>(
            h1H, h1L, 1024, W2h, W2l, enc_b2, h2H, h2L, 1024);
        mfma_gemm<3, 64, 2, 0><<<dim3(mt), dim3(256), 0, stream>>>(
            h2H, h2L, 1024, W3h, W3l, enc_b3, mz, nullptr, 64);

        xz_pre<<<dim3(M / 16), dim3(256), 0, stream>>>(state + (size_t)r0 * SDIM, xz);

        zero_ctr<<<dim3(1), dim3(64), 0, stream>>>(ctr);
        vq_latent<<<dim3(mt), dim3(256), 0, stream>>>(
            mz, codebook, cbn, mean_w, mean_b, logstd_w, logstd_b,
            eps + (size_t)r0 * LDIM,
            mean_out + (size_t)r0 * LDIM, std_out + (size_t)r0 * LDIM, xz,
            ctr, flag_list);
        fix_rows<<<dim3(1024), dim3(256), 0, stream>>>(
            ctr, flag_list, r0, state, action, eps,
            enc_w1, enc_b1, enc_w2, enc_b2, enc_w3, enc_b3,
            mean_w, mean_b, logstd_w, logstd_b, codebook, cbn,
            mean_out, std_out, xz);

        // decoder: plain bf16 MFMA
        mfma_gemm<1, 128, 1, 0><<<dim3(mt * 8), dim3(256), 0, stream>>>(
            xz, nullptr, 128, W4h, nullptr, dec_b1, hc, nullptr, 1024);
        mfma_gemm<1, 128, 1, 0><<<dim3(mt * 8), dim3(256), 0, stream>>>(
            hc, nullptr, 1024, W5h, nullptr, dec_b2, hd, nullptr, 1024);
        mfma_gemm<1, 32, 2, 1><<<dim3(mt), dim3(256), 0, stream>>>(
            hd, nullptr, 1024, W6h, nullptr, dec_b3,
            u_out + (size_t)r0 * ADIM, nullptr, 32);
    }
}